// Round 17
// baseline (173.681 us; speedup 1.0000x reference)
//
#include <hip/hip_runtime.h>
#include <stdint.h>

// Conv2d as implicit GEMM, bf16 MFMA.
// R17: NO LDS, NO barriers; REGISTER double-buffered direct-global fragments.
// Per tile: prefetch t+1's A (8x line-efficient 1KB wave-loads) + B (4x 1KB
// coalesced) into the alternate register set, then 32 MFMA on the current set
// -> L2 latency hidden under the 620-cyc MFMA cluster. Pure dataflow.
// GEMM: M=100352, N=256, K=1152 (k=(kh*3+kw)*128+ci). 36 K-tiles. Grid 784.

#define CIN   128
#define HW_   56
#define CO_   256
#define KSZ   1152
#define IMGHW 3136
#define HP    58
#define NT    36
#define XT_BYTES ((size_t)32 * HP * HP * CIN * 2)   // 27,557,888
#define WP_BYTES ((size_t)CO_ * KSZ * 2)            // 589,824
#define WS_NEED  (XT_BYTES + WP_BYTES)
#define XBLKS    (32 * HP)
#define PBLKS    ((CO_ * KSZ) / 256)

typedef __attribute__((ext_vector_type(8)))  __bf16 bf16x8;
typedef __attribute__((ext_vector_type(4)))  float  f32x4;
typedef __attribute__((ext_vector_type(8)))  unsigned short ushort8;

__device__ __forceinline__ unsigned short f2bf(float f) {
    unsigned int u = __float_as_uint(f);
    u += 0x7fffu + ((u >> 16) & 1u);   // RNE
    return (unsigned short)(u >> 16);
}

// ---- fused prep: xform (blocks 0..XBLKS-1) + fragment-contiguous weight pack.
// Pack (R14-verified): wp2[((t*16 + cog)*64 + lane)*8 + e] = bf16(W[co][k]),
//   co = cog*16 + (lane&15), k = t*32 + (lane>>4)*8 + e,
//   W[co][k] = w[(co*128 + (k&127))*9 + (k>>7)].
__global__ __launch_bounds__(256)
void prep(const float* __restrict__ x, unsigned short* __restrict__ xt,
          const float* __restrict__ w, unsigned short* __restrict__ wp2) {
    const int t = threadIdx.x;
    if (blockIdx.x >= XBLKS) {
        int o = (blockIdx.x - XBLKS) * 256 + t;
        int e    = o & 7;
        int lane = (o >> 3) & 63;
        int cog  = (o >> 9) & 15;
        int tt   = o >> 13;
        int co = cog * 16 + (lane & 15);
        int k  = tt * 32 + (lane >> 4) * 8 + e;
        wp2[o] = f2bf(w[(co * CIN + (k & 127)) * 9 + (k >> 7)]);
        return;
    }
    const int nb = blockIdx.x;
    const int n  = nb / HP;
    const int hp = nb - n * HP;
    unsigned short* orow = xt + ((size_t)n * HP + hp) * (HP * CIN);

    if (hp == 0 || hp == HP - 1) {
        for (int i = t; i < (HP * CIN) / 8; i += 256)
            ((ushort8*)orow)[i] = (ushort8){0, 0, 0, 0, 0, 0, 0, 0};
        return;
    }
    const int h = hp - 1;
    __shared__ ushort2 T[CIN][31];
    {
        const int ci = t >> 1, part = t & 1;
        const float* src = x + (((size_t)n * CIN + ci) * IMGHW + h * HW_ + part * 28);
        #pragma unroll
        for (int j = 0; j < 7; ++j) {
            float4 v = *(const float4*)(src + 4 * j);
            T[ci][part * 14 + 2 * j]     = (ushort2){f2bf(v.x), f2bf(v.y)};
            T[ci][part * 14 + 2 * j + 1] = (ushort2){f2bf(v.z), f2bf(v.w)};
        }
    }
    __syncthreads();
    const int wpg = t >> 4, cig = t & 15;
    const int ci0 = cig * 8;
    for (int wp_ = wpg; wp_ < HP; wp_ += 16) {
        ushort8 v = (ushort8){0, 0, 0, 0, 0, 0, 0, 0};
        const int w_ = wp_ - 1;
        if ((unsigned)w_ < (unsigned)HW_) {
            #pragma unroll
            for (int e = 0; e < 8; ++e) {
                ushort2 p = T[ci0 + e][w_ >> 1];
                v[e] = (w_ & 1) ? p.y : p.x;
            }
        }
        *(ushort8*)(orow + wp_ * CIN + ci0) = v;
    }
}

// ---- main conv: 256x128 block, 4 waves (2m x 2n), wave 128x64, no LDS,
// register-double-buffered fragments (A and B prefetched 1 tile ahead).
__global__ __launch_bounds__(256, 2)
void conv17(const unsigned short* __restrict__ xt,
            const unsigned short* __restrict__ wp2,
            float* __restrict__ out)
{
    const int tid  = threadIdx.x;
    const int lane = tid & 63;
    const int wid  = tid >> 6;

    int bid = blockIdx.x;
    int flat = (bid & 7) * 98 + (bid >> 3);     // XCD swizzle, 784 = 8*98 bijective
    const int mt_ = flat >> 1;                  // pair shares A-panel (L2)
    const int n0  = (flat & 1) << 7;
    const int m0  = mt_ << 8;

    const int fr = lane & 15, fg = lane >> 4;
    const int wm0 = (wid >> 1) << 7;            // 0 / 128
    const int wn0 = (wid & 1) << 6;             // 0 / 64

    // ---- A fragment global bases (R15-verified): lane reads
    // xt_row(m)[tap-window + (t&3)*64 + fg*16 ..16); 16 rows x 4 chunks/inst
    // = 16 fully-consumed 64B lines per wave-load.
    uint32_t aBase[8];
    #pragma unroll
    for (int mf = 0; mf < 8; ++mf) {
        int m = m0 + wm0 + mf * 16 + fr;
        int n = m / IMGHW;
        int rem = m - n * IMGHW;
        int h = rem / HW_;
        int w = rem - h * HW_;
        aBase[mf] = (uint32_t)((((n * HP + h) * HP + w) << 8) + (fg << 4));
    }

    // ---- B fragment-contiguous global base (R14-verified) ----
    const int nfgB = (n0 + wn0) >> 4;
    const unsigned short* wpb = wp2 + (size_t)lane * 8;
    const char* xtc = (const char*)xt;

    f32x4 acc[8][4];
    #pragma unroll
    for (int i = 0; i < 8; ++i)
        #pragma unroll
        for (int j = 0; j < 4; ++j)
            acc[i][j] = (f32x4){0.f, 0.f, 0.f, 0.f};

    ushort8 aA[8], bA[4], aB[8], bB[4];

    #define SLICE(t) ((uint32_t)(((((((t) >> 2) * 11) >> 5) * HP + \
        (((t) >> 2) - ((((t) >> 2) * 11) >> 5) * 3)) << 8) + (((t) & 3) << 6)))

    #define LOADT(A_, B_, t) do { \
        const uint32_t asl_ = SLICE(t); \
        _Pragma("unroll") for (int nf_ = 0; nf_ < 4; ++nf_) \
            B_[nf_] = *(const ushort8*)(wpb + \
                (size_t)(((t) * 16 + nfgB + nf_) * 64) * 8); \
        _Pragma("unroll") for (int mf_ = 0; mf_ < 8; ++mf_) \
            A_[mf_] = *(const ushort8*)(xtc + aBase[mf_] + asl_); \
    } while (0)

    #define MMTILE(A_, B_) do { \
        _Pragma("unroll") for (int mf_ = 0; mf_ < 8; ++mf_) \
            _Pragma("unroll") for (int nf_ = 0; nf_ < 4; ++nf_) \
                acc[mf_][nf_] = __builtin_amdgcn_mfma_f32_16x16x32_bf16( \
                    __builtin_bit_cast(bf16x8, B_[nf_]), \
                    __builtin_bit_cast(bf16x8, A_[mf_]), \
                    acc[mf_][nf_], 0, 0, 0); \
    } while (0)

    // ---- prologue: tile0 -> set A ----
    LOADT(aA, bA, 0);

    #pragma unroll 1
    for (int tt = 0; tt < NT; tt += 2) {
        // tile tt: prefetch tt+1 into set B, compute on set A
        if (tt + 1 < NT) LOADT(aB, bB, tt + 1);
        __builtin_amdgcn_sched_barrier(0);
        MMTILE(aA, bA);
        // tile tt+1: prefetch tt+2 into set A, compute on set B
        if (tt + 2 < NT) LOADT(aA, bA, tt + 2);
        __builtin_amdgcn_sched_barrier(0);
        MMTILE(aB, bB);
    }

    // ---- epilogue: direct stores; D row=co, col=m; lanes 0-15 contiguous in w
    const int mwave = m0 + wm0;
    const int co0 = n0 + wn0 + (fg << 2);
    #pragma unroll
    for (int mf = 0; mf < 8; ++mf) {
        int m = mwave + mf * 16 + fr;
        int n = m / IMGHW;
        int hwr = m - n * IMGHW;
        uint32_t basem = (uint32_t)(n * (CO_ * IMGHW) + hwr);
        #pragma unroll
        for (int nf = 0; nf < 4; ++nf)
            #pragma unroll
            for (int q = 0; q < 4; ++q)
                out[basem + (uint32_t)(co0 + nf * 16 + q) * IMGHW] = acc[mf][nf][q];
    }
    #undef SLICE
    #undef LOADT
    #undef MMTILE
}

// ================= fallback (round-1 kernel, used if ws too small) ==========
#define BM    64
#define BK    32
#define NSTEP 36
#define LDSP  40

template<bool PACKED>
__global__ __launch_bounds__(256, 2)
void conv_fb(const float* __restrict__ x,
             const float* __restrict__ wraw,
             const unsigned short* __restrict__ wp,
             float* __restrict__ out)
{
    __shared__ __align__(16) unsigned short Al[2][BM][LDSP];
    __shared__ __align__(16) unsigned short Bl[2][CO_][LDSP];

    const int tid  = threadIdx.x;
    const int lane = tid & 63;
    const int wid  = tid >> 6;

    const int mb    = blockIdx.x;
    const int n_img = mb / 49;
    const int hw0   = (mb - n_img * 49) * BM;

    const int mm = lane;
    const int hw = hw0 + mm;
    const int h  = hw / HW_;
    const int w_ = hw - h * HW_;

    const int bco  = tid >> 2;
    const int bkkg = tid & 3;

    float   aPF[8];
    ushort8 bPF[4];

    auto loadA = [&](int step) {
        int khkw = step >> 2;
        int kh = khkw / 3, kw = khkw - (khkw / 3) * 3;
        int ci0 = (step & 3) * BK + wid * 8;
        int ih = h + kh - 1, iw = w_ + kw - 1;
        bool valid = ((unsigned)ih < (unsigned)HW_) && ((unsigned)iw < (unsigned)HW_);
        const float* px = x + (((size_t)(n_img * CIN + ci0) * HW_ + ih) * HW_ + iw);
        #pragma unroll
        for (int e = 0; e < 8; ++e)
            aPF[e] = valid ? px[e * IMGHW] : 0.f;
    };
    auto writeA = [&](int buf) {
        ushort8 v;
        #pragma unroll
        for (int e = 0; e < 8; ++e) v[e] = f2bf(aPF[e]);
        *(ushort8*)&Al[buf][mm][wid * 8] = v;
    };
    auto loadB = [&](int step) {
        int khkw = step >> 2;
        int ci0 = (step & 3) * BK + bkkg * 8;
        #pragma unroll
        for (int r = 0; r < 4; ++r) {
            int co = r * 64 + bco;
            ushort8 v;
            #pragma unroll
            for (int e = 0; e < 8; ++e)
                v[e] = f2bf(wraw[(co * CIN + ci0 + e) * 9 + khkw]);
            bPF[r] = v;
        }
    };
    auto writeB = [&](int buf) {
        #pragma unroll
        for (int r = 0; r < 4; ++r)
            *(ushort8*)&Bl[buf][r * 64 + bco][bkkg * 8] = bPF[r];
    };

    f32x4 acc[4][4];
    #pragma unroll
    for (int i = 0; i < 4; ++i)
        #pragma unroll
        for (int j = 0; j < 4; ++j)
            acc[i][j] = (f32x4){0.f, 0.f, 0.f, 0.f};

    const int frow = lane & 15;
    const int fk   = (lane >> 4) * 8;

    loadA(0); loadB(0);
    writeA(0); writeB(0);
    __syncthreads();

    for (int s = 0; s < NSTEP; ++s) {
        const int cur = s & 1;
        if (s + 1 < NSTEP) { loadA(s + 1); loadB(s + 1); }

        ushort8 aF[4], bF[4];
        #pragma unroll
        for (int i = 0; i < 4; ++i)
            aF[i] = *(const ushort8*)&Bl[cur][wid * 64 + i * 16 + frow][fk];
        #pragma unroll
        for (int j = 0; j < 4; ++j)
            bF[j] = *(const ushort8*)&Al[cur][j * 16 + frow][fk];

        #pragma unroll
        for (int i = 0; i < 4; ++i)
            #pragma unroll
            for (int j = 0; j < 4; ++j)
                acc[i][j] = __builtin_amdgcn_mfma_f32_16x16x32_bf16(
                    __builtin_bit_cast(bf16x8, aF[i]),
                    __builtin_bit_cast(bf16x8, bF[j]),
                    acc[i][j], 0, 0, 0);

        if (s + 1 < NSTEP) { writeA(cur ^ 1); writeB(cur ^ 1); }
        __syncthreads();
    }

    float* ob = out + (size_t)n_img * (CO_ * IMGHW) + hw0;
    #pragma unroll
    for (int i = 0; i < 4; ++i) {
        int co0 = wid * 64 + i * 16 + (lane >> 4) * 4;
        #pragma unroll
        for (int j = 0; j < 4; ++j) {
            int mcol = j * 16 + (lane & 15);
            #pragma unroll
            for (int q = 0; q < 4; ++q)
                ob[(size_t)(co0 + q) * IMGHW + mcol] = acc[i][j][q];
        }
    }
}

extern "C" void kernel_launch(void* const* d_in, const int* in_sizes, int n_in,
                              void* d_out, int out_size, void* d_ws, size_t ws_size,
                              hipStream_t stream) {
    (void)in_sizes; (void)n_in; (void)out_size;
    const float* x  = (const float*)d_in[0];
    const float* wt = (const float*)d_in[1];
    float* out = (float*)d_out;

    if (ws_size >= WS_NEED) {
        unsigned short* xt  = (unsigned short*)d_ws;
        unsigned short* wp2 = (unsigned short*)((char*)d_ws + XT_BYTES);
        prep<<<XBLKS + PBLKS, 256, 0, stream>>>(x, xt, wt, wp2);
        conv17<<<784, 256, 0, stream>>>(xt, wp2, out);
    } else {
        conv_fb<false><<<100352 / BM, 256, 0, stream>>>(x, wt, nullptr, out);
    }
}

// Round 18
// 95.967 us; speedup vs baseline: 1.8098x; 1.8098x over previous
//
#include <hip/hip_runtime.h>
#include <stdint.h>

// Conv2d as implicit GEMM, bf16 MFMA.
// R19: R10 kernel (128x128 tile, BK=32, 4 waves of 64x64, 32KB LDS dbuf,
// zero-conflict paired-row layout) with __launch_bounds__(256,4):
// 4 blocks/CU = 16 waves/CU = 4 waves/SIMD (regs 56V+64A=120 <= 128).
// Pure TLP probe: double R14's residency at R10's verified structure.
// GEMM: M=100352, N=256, K=1152 (k=(kh*3+kw)*128+ci). 36 K-tiles. Grid 1568.

#define CIN   128
#define HW_   56
#define CO_   256
#define KSZ   1152
#define IMGHW 3136
#define HP    58
#define XT_BYTES ((size_t)32 * HP * HP * CIN * 2)   // 27,557,888
#define WP_BYTES ((size_t)CO_ * KSZ * 2)            // 589,824
#define WS_NEED  (XT_BYTES + WP_BYTES)
#define XBLKS    (32 * HP)
#define PBLKS    ((CO_ * KSZ) / 256)

typedef __attribute__((ext_vector_type(8))) __bf16 bf16x8;
typedef __attribute__((ext_vector_type(4))) float f32x4;
typedef __attribute__((ext_vector_type(8))) unsigned short ushort8;

__device__ __forceinline__ unsigned short f2bf(float f) {
    unsigned int u = __float_as_uint(f);
    u += 0x7fffu + ((u >> 16) & 1u);   // RNE
    return (unsigned short)(u >> 16);
}

__device__ __forceinline__ void gl2lds16(const void* g, void* l) {
    __builtin_amdgcn_global_load_lds(
        (const __attribute__((address_space(1))) void*)g,
        (__attribute__((address_space(3))) void*)l, 16, 0, 0);
}

// ---- fused prep: xform (blocks 0..XBLKS-1) + row-major weight pack [co][k]
__global__ __launch_bounds__(256)
void prep(const float* __restrict__ x, unsigned short* __restrict__ xt,
          const float* __restrict__ w, unsigned short* __restrict__ wp) {
    const int t = threadIdx.x;
    if (blockIdx.x >= XBLKS) {
        int idx = (blockIdx.x - XBLKS) * 256 + t;
        int co = idx / KSZ;
        int k  = idx - co * KSZ;
        wp[idx] = f2bf(w[(co * CIN + (k & 127)) * 9 + (k >> 7)]);
        return;
    }
    const int nb = blockIdx.x;
    const int n  = nb / HP;
    const int hp = nb - n * HP;
    unsigned short* orow = xt + ((size_t)n * HP + hp) * (HP * CIN);

    if (hp == 0 || hp == HP - 1) {
        for (int i = t; i < (HP * CIN) / 8; i += 256)
            ((ushort8*)orow)[i] = (ushort8){0, 0, 0, 0, 0, 0, 0, 0};
        return;
    }
    const int h = hp - 1;
    __shared__ ushort2 T[CIN][31];
    {
        const int ci = t >> 1, part = t & 1;
        const float* src = x + (((size_t)n * CIN + ci) * IMGHW + h * HW_ + part * 28);
        #pragma unroll
        for (int j = 0; j < 7; ++j) {
            float4 v = *(const float4*)(src + 4 * j);
            T[ci][part * 14 + 2 * j]     = (ushort2){f2bf(v.x), f2bf(v.y)};
            T[ci][part * 14 + 2 * j + 1] = (ushort2){f2bf(v.z), f2bf(v.w)};
        }
    }
    __syncthreads();
    const int wpg = t >> 4, cig = t & 15;
    const int ci0 = cig * 8;
    for (int wp_ = wpg; wp_ < HP; wp_ += 16) {
        ushort8 v = (ushort8){0, 0, 0, 0, 0, 0, 0, 0};
        const int w_ = wp_ - 1;
        if ((unsigned)w_ < (unsigned)HW_) {
            #pragma unroll
            for (int e = 0; e < 8; ++e) {
                ushort2 p = T[ci0 + e][w_ >> 1];
                v[e] = (w_ & 1) ? p.y : p.x;
            }
        }
        *(ushort8*)(orow + wp_ * CIN + ci0) = v;
    }
}

// ---- main conv: 128x128 tile, BK=32, 4 waves (2m x 2n), wave 64x64
// LDS buf (16KB): A [64 r2][128B] @0, B [64 r2][128B] @8K (R10-verified).
__global__ __launch_bounds__(256, 4)
void conv19(const unsigned short* __restrict__ xt,
            const unsigned short* __restrict__ wpk,
            float* __restrict__ out)
{
    __shared__ __align__(16) char lds[2][16384];   // 32 KiB -> 4 blocks/CU

    const int tid  = threadIdx.x;
    const int lane = tid & 63;
    const int wid  = tid >> 6;

    int bid = blockIdx.x;
    int flat = (bid & 7) * 196 + (bid >> 3);   // XCD swizzle, 1568 = 8*196 bijective
    const int mt = flat >> 1;                   // adjacent pair shares A-panel
    const int n0 = (flat & 1) << 7;
    const int m0 = mt << 7;

    // ---- staging source offsets: 4 gl2lds/thread/tile (R10-verified) ----
    const int lc = (tid & 7) ^ ((tid >> 3) & 7);
    uint32_t abase[2], bbase[2];
    #pragma unroll
    for (int p = 0; p < 2; ++p) {
        int r  = (((tid >> 3) + 32 * p) << 1) + (lc >> 2);
        int m  = m0 + r;
        int n  = m / IMGHW;
        int rem = m - n * IMGHW;
        int h  = rem / HW_;
        int w  = rem - h * HW_;
        abase[p] = (uint32_t)((((n * HP + h) * HP + w) << 8) + ((lc & 3) << 4));
        bbase[p] = (uint32_t)((n0 + r) * (KSZ * 2) + ((lc & 3) << 4));
    }

    // ---- fragment LDS offsets (R10-verified, measured 0 conflicts) ----
    const int fr = lane & 15, fg = lane >> 4;
    const int cp = (((fr & 1) << 2) | fg) ^ ((fr >> 1) & 7);
    const int wm0 = (wid >> 1) << 6;            // 0 / 64
    const int wn0 = (wid & 1) << 6;             // 0 / 64
    const int aB = (((wm0 >> 1) + (fr >> 1)) << 7) + (cp << 4);          // + mf*1024
    const int bB = 8192 + (((wn0 >> 1) + (fr >> 1)) << 7) + (cp << 4);   // + nf*1024

    const char* xtc = (const char*)xt;
    const char* wpc = (const char*)wpk;

    f32x4 acc[4][4];
    #pragma unroll
    for (int i = 0; i < 4; ++i)
        #pragma unroll
        for (int j = 0; j < 4; ++j)
            acc[i][j] = (f32x4){0.f, 0.f, 0.f, 0.f};

    auto STAGE = [&](int t, int buf) {          // K-tile t (BK=32)
        int tap = t >> 2;
        int kh = (tap * 11) >> 5;               // tap/3 for tap<9
        int kw = tap - kh * 3;
        uint32_t asl = (uint32_t)(((kh * HP + kw) << 8) + ((t & 3) << 6));
        uint32_t bsl = (uint32_t)(t << 6);
        char* L = &lds[buf][0];
        gl2lds16(xtc + abase[0] + asl, L + tid * 16);
        gl2lds16(xtc + abase[1] + asl, L + 4096 + tid * 16);
        gl2lds16(wpc + bbase[0] + bsl, L + 8192 + tid * 16);
        gl2lds16(wpc + bbase[1] + bsl, L + 12288 + tid * 16);
    };

    STAGE(0, 0);
    __syncthreads();

    #pragma unroll 1
    for (int t = 0; t < 36; ++t) {
        if (t < 35) STAGE(t + 1, (t + 1) & 1);
        const char* L = &lds[t & 1][0];
        ushort8 a[4], b[4];
        #pragma unroll
        for (int nf = 0; nf < 4; ++nf)
            b[nf] = *(const ushort8*)(L + bB + nf * 1024);
        #pragma unroll
        for (int mf = 0; mf < 4; ++mf)
            a[mf] = *(const ushort8*)(L + aB + mf * 1024);
        #pragma unroll
        for (int mf = 0; mf < 4; ++mf)
            #pragma unroll
            for (int nf = 0; nf < 4; ++nf)
                acc[mf][nf] = __builtin_amdgcn_mfma_f32_16x16x32_bf16(
                    __builtin_bit_cast(bf16x8, b[nf]),
                    __builtin_bit_cast(bf16x8, a[mf]),
                    acc[mf][nf], 0, 0, 0);
        __syncthreads();
    }

    // ---- epilogue: direct stores; D row=co, col=m; lanes 0-15 contiguous in w
    const int mwave = m0 + wm0;
    const int co0 = n0 + wn0 + (fg << 2);
    #pragma unroll
    for (int mf = 0; mf < 4; ++mf) {
        int m = mwave + mf * 16 + fr;
        int n = m / IMGHW;
        int hwr = m - n * IMGHW;
        uint32_t basem = (uint32_t)(n * (CO_ * IMGHW) + hwr);
        #pragma unroll
        for (int nf = 0; nf < 4; ++nf)
            #pragma unroll
            for (int q = 0; q < 4; ++q)
                out[basem + (uint32_t)(co0 + nf * 16 + q) * IMGHW] = acc[mf][nf][q];
    }
}

// ================= fallback (round-1 kernel, used if ws too small) ==========
#define BM    64
#define BK    32
#define NSTEP 36
#define LDSP  40

template<bool PACKED>
__global__ __launch_bounds__(256, 2)
void conv_fb(const float* __restrict__ x,
             const float* __restrict__ wraw,
             const unsigned short* __restrict__ wp,
             float* __restrict__ out)
{
    __shared__ __align__(16) unsigned short Al[2][BM][LDSP];
    __shared__ __align__(16) unsigned short Bl[2][CO_][LDSP];

    const int tid  = threadIdx.x;
    const int lane = tid & 63;
    const int wid  = tid >> 6;

    const int mb    = blockIdx.x;
    const int n_img = mb / 49;
    const int hw0   = (mb - n_img * 49) * BM;

    const int mm = lane;
    const int hw = hw0 + mm;
    const int h  = hw / HW_;
    const int w_ = hw - h * HW_;

    const int bco  = tid >> 2;
    const int bkkg = tid & 3;

    float   aPF[8];
    ushort8 bPF[4];

    auto loadA = [&](int step) {
        int khkw = step >> 2;
        int kh = khkw / 3, kw = khkw - (khkw / 3) * 3;
        int ci0 = (step & 3) * BK + wid * 8;
        int ih = h + kh - 1, iw = w_ + kw - 1;
        bool valid = ((unsigned)ih < (unsigned)HW_) && ((unsigned)iw < (unsigned)HW_);
        const float* px = x + (((size_t)(n_img * CIN + ci0) * HW_ + ih) * HW_ + iw);
        #pragma unroll
        for (int e = 0; e < 8; ++e)
            aPF[e] = valid ? px[e * IMGHW] : 0.f;
    };
    auto writeA = [&](int buf) {
        ushort8 v;
        #pragma unroll
        for (int e = 0; e < 8; ++e) v[e] = f2bf(aPF[e]);
        *(ushort8*)&Al[buf][mm][wid * 8] = v;
    };
    auto loadB = [&](int step) {
        int khkw = step >> 2;
        int ci0 = (step & 3) * BK + bkkg * 8;
        #pragma unroll
        for (int r = 0; r < 4; ++r) {
            int co = r * 64 + bco;
            ushort8 v;
            #pragma unroll
            for (int e = 0; e < 8; ++e)
                v[e] = f2bf(wraw[(co * CIN + ci0 + e) * 9 + khkw]);
            bPF[r] = v;
        }
    };
    auto writeB = [&](int buf) {
        #pragma unroll
        for (int r = 0; r < 4; ++r)
            *(ushort8*)&Bl[buf][r * 64 + bco][bkkg * 8] = bPF[r];
    };

    f32x4 acc[4][4];
    #pragma unroll
    for (int i = 0; i < 4; ++i)
        #pragma unroll
        for (int j = 0; j < 4; ++j)
            acc[i][j] = (f32x4){0.f, 0.f, 0.f, 0.f};

    const int frow = lane & 15;
    const int fk   = (lane >> 4) * 8;

    loadA(0); loadB(0);
    writeA(0); writeB(0);
    __syncthreads();

    for (int s = 0; s < NSTEP; ++s) {
        const int cur = s & 1;
        if (s + 1 < NSTEP) { loadA(s + 1); loadB(s + 1); }

        ushort8 aF[4], bF[4];
        #pragma unroll
        for (int i = 0; i < 4; ++i)
            aF[i] = *(const ushort8*)&Bl[cur][wid * 64 + i * 16 + frow][fk];
        #pragma unroll
        for (int j = 0; j < 4; ++j)
            bF[j] = *(const ushort8*)&Al[cur][j * 16 + frow][fk];

        #pragma unroll
        for (int i = 0; i < 4; ++i)
            #pragma unroll
            for (int j = 0; j < 4; ++j)
                acc[i][j] = __builtin_amdgcn_mfma_f32_16x16x32_bf16(
                    __builtin_bit_cast(bf16x8, aF[i]),
                    __builtin_bit_cast(bf16x8, bF[j]),
                    acc[i][j], 0, 0, 0);

        if (s + 1 < NSTEP) { writeA(cur ^ 1); writeB(cur ^ 1); }
        __syncthreads();
    }

    float* ob = out + (size_t)n_img * (CO_ * IMGHW) + hw0;
    #pragma unroll
    for (int i = 0; i < 4; ++i) {
        int co0 = wid * 64 + i * 16 + (lane >> 4) * 4;
        #pragma unroll
        for (int j = 0; j < 4; ++j) {
            int mcol = j * 16 + (lane & 15);
            #pragma unroll
            for (int q = 0; q < 4; ++q)
                ob[(size_t)(co0 + q) * IMGHW + mcol] = acc[i][j][q];
        }
    }
}

extern "C" void kernel_launch(void* const* d_in, const int* in_sizes, int n_in,
                              void* d_out, int out_size, void* d_ws, size_t ws_size,
                              hipStream_t stream) {
    (void)in_sizes; (void)n_in; (void)out_size;
    const float* x  = (const float*)d_in[0];
    const float* wt = (const float*)d_in[1];
    float* out = (float*)d_out;

    if (ws_size >= WS_NEED) {
        unsigned short* xt  = (unsigned short*)d_ws;
        unsigned short* wpk = (unsigned short*)((char*)d_ws + XT_BYTES);
        prep<<<XBLKS + PBLKS, 256, 0, stream>>>(x, xt, wt, wpk);
        conv19<<<1568, 256, 0, stream>>>(xt, wpk, out);
    } else {
        conv_fb<false><<<100352 / BM, 256, 0, stream>>>(x, wt, nullptr, out);
    }
}